// Round 3
// baseline (145.434 us; speedup 1.0000x reference)
//
#include <hip/hip_runtime.h>
#include <hip/hip_cooperative_groups.h>

namespace cg = cooperative_groups;

#define NB   8
#define CIN  32
#define HH   28
#define WW   28
#define OC   64
#define HWSZ (HH*WW)            // 784
#define TOTAL (NB*OC*HWSZ)      // 401408
#define CNT  (NB*HWSZ)          // 6272 elements per channel for BN stats

#define TROWS 4                 // staged input rows: h0-1 .. h0+2
#define TCOLS 32                // padded cols (-1..30); power-of-2 -> shift indexing
#define TSZ  (CIN*TROWS*TCOLS)  // 4096 floats = 16 KB LDS

#define CPW  2                  // output channels per wave (4 waves -> 8 ch/block)
#define CHGRP 8                 // 8 channel groups of 8
#define NCOPY 32                // scattered stat accumulator copies (32 x 128 doubles)
#define GRID (NB*14*CHGRP)      // 896 blocks -> 3584 waves; coop-resident (needs 4/CU, have 8)

__global__ __launch_bounds__(256) void fused_kernel(
    const float* __restrict__ x, const float* __restrict__ Wt,
    double* __restrict__ Sbuf,
    const float* __restrict__ gamma, const float* __restrict__ beta,
    float* __restrict__ out)
{
    __shared__ float xs[TSZ];
    const int t     = threadIdx.x;
    const int bid   = blockIdx.x;
    const int chgrp = bid & (CHGRP-1);
    const int sp    = bid >> 3;          // spatial tile index: rp + 14*n
    const int rp    = sp % 14;
    const int n     = bid / (CHGRP * 14);
    const int h0    = rp * 2;
    const int copy  = sp & (NCOPY-1);    // spreads each channel's adds over all copies

    // ---- stage x strip: ALL 32 channels, rows h0-1..h0+2, cols -1..30 ----
    #pragma unroll 4
    for (int i = t; i < TSZ; i += 256) {
        int cc  = i >> 7;          // /128
        int r   = (i >> 5) & 3;    // /32 % 4
        int col = i & 31;
        int hh  = h0 - 1 + r;
        int ww  = col - 1;
        float v = 0.0f;
        if (hh >= 0 && hh < HH && (unsigned)ww < (unsigned)WW)
            v = x[((n*CIN + cc)*HH + hh)*WW + ww];
        xs[i] = v;
    }
    __syncthreads();

    const int lane  = t & 63;
    const int g     = __builtin_amdgcn_readfirstlane(t >> 6); // wave id, uniform
    const bool valid = lane < 56;                 // 2 rows x 28 cols
    const int p     = valid ? lane : 0;
    const int pr    = p / WW;                     // 0 or 1
    const int pw    = p % WW;
    const int o_base = chgrp*8 + g*CPW;
    const int b0    = pr*TCOLS + pw;              // base inside channel 0

    float acc0 = 0.0f, acc1 = 0.0f;

    // 9 LDS reads per cc feed 36 VALU; unroll 4 keeps 4 independent
    // ds_read/s_load batches in flight (lgkmcnt overlap at low occupancy).
    #pragma unroll 4
    for (int cc = 0; cc < CIN; ++cc) {
        float xr[9];
        #pragma unroll
        for (int dr = 0; dr < 3; ++dr)
            #pragma unroll
            for (int dc = 0; dc < 3; ++dc)
                xr[dr*3+dc] = xs[(cc << 7) + b0 + (dr << 5) + dc];
        const float* wp0 = Wt + ((o_base    )*CIN + cc)*9; // wave-uniform -> s_load
        const float* wp1 = Wt + ((o_base + 1)*CIN + cc)*9;
        #pragma unroll
        for (int j = 0; j < 9; ++j) acc0 += __builtin_fabsf(xr[j] - wp0[j]);
        #pragma unroll
        for (int j = 0; j < 9; ++j) acc1 += __builtin_fabsf(xr[j] - wp1[j]);
    }

    // ---- fused BN stats: f32 wave-reduce, f64 atomics scattered over NCOPY ----
    {
        float v0 = valid ? -acc0 : 0.0f;
        float v1 = valid ? -acc1 : 0.0f;
        float s0 = v0, q0 = v0*v0, s1 = v1, q1 = v1*v1;
        #pragma unroll
        for (int off = 32; off >= 1; off >>= 1) {
            s0 += __shfl_xor(s0, off, 64);
            q0 += __shfl_xor(q0, off, 64);
            s1 += __shfl_xor(s1, off, 64);
            q1 += __shfl_xor(q1, off, 64);
        }
        if (lane == 0) {
            double* Sc = Sbuf + copy*128;
            atomicAdd(&Sc[     o_base    ], (double)s0);
            atomicAdd(&Sc[64 + o_base    ], (double)q0);
            atomicAdd(&Sc[     o_base + 1], (double)s1);
            atomicAdd(&Sc[64 + o_base + 1], (double)q1);
        }
    }

    cg::this_grid().sync();   // all stats visible (device-scope atomics + grid fence)

    // ---- finalize: each 32-lane half reduces one channel's NCOPY partials ----
    const int half = lane >> 5;          // 0 -> o_base, 1 -> o_base+1
    const int cidx = lane & 31;          // copy index (one per lane)
    const int ch   = o_base + half;
    double Sv  = Sbuf[cidx*128 + ch];
    double S2v = Sbuf[cidx*128 + 64 + ch];
    #pragma unroll
    for (int off = 16; off >= 1; off >>= 1) {   // stays within each 32-lane group
        Sv  += __shfl_xor(Sv,  off, 64);
        S2v += __shfl_xor(S2v, off, 64);
    }
    double mean = Sv  * (1.0 / CNT);
    double var  = S2v * (1.0 / CNT) - mean * mean;
    double gs   = (double)gamma[ch] / sqrt(var + 1e-5);
    float scl_o = (float)gs;
    float sh_o  = (float)((double)beta[ch] - mean * gs);
    float scl_x = __shfl_xor(scl_o, 32, 64);
    float sh_x  = __shfl_xor(sh_o,  32, 64);
    float scl0 = half ? scl_x : scl_o;
    float sh0  = half ? sh_x  : sh_o;
    float scl1 = half ? scl_o : scl_x;
    float sh1  = half ? sh_o  : sh_x;

    // ---- write normalized output straight from registers (no raw buffer) ----
    if (valid) {
        const int base = (h0 + pr)*WW + pw;
        out[(n*OC + o_base    )*HWSZ + base] = (-acc0)*scl0 + sh0;
        out[(n*OC + o_base + 1)*HWSZ + base] = (-acc1)*scl1 + sh1;
    }
}

extern "C" void kernel_launch(void* const* d_in, const int* in_sizes, int n_in,
                              void* d_out, int out_size, void* d_ws, size_t ws_size,
                              hipStream_t stream) {
    const float* x     = (const float*)d_in[0];
    const float* Wt    = (const float*)d_in[1];
    const float* gamma = (const float*)d_in[2];
    const float* beta  = (const float*)d_in[3];
    float* out  = (float*)d_out;
    double* Sbuf = (double*)d_ws;       // 32 KB of stat accumulators, nothing else

    hipMemsetAsync(d_ws, 0, NCOPY*128*sizeof(double), stream);

    void* args[] = { (void*)&x, (void*)&Wt, (void*)&Sbuf,
                     (void*)&gamma, (void*)&beta, (void*)&out };
    hipLaunchCooperativeKernel(reinterpret_cast<void*>(fused_kernel),
                               dim3(GRID), dim3(256), args, 0, stream);
}

// Round 4
// 80.743 us; speedup vs baseline: 1.8012x; 1.8012x over previous
//
#include <hip/hip_runtime.h>

#define NB   8
#define CIN  32
#define HH   28
#define WW   28
#define OC   64
#define HWSZ (HH*WW)            // 784
#define TOTAL (NB*OC*HWSZ)      // 401408
#define CNT  (NB*HWSZ)          // 6272 elements per channel for BN stats

#define TROWS 4                 // staged input rows: h0-1 .. h0+2
#define TCOLS 32                // padded cols (-1..30); power-of-2 -> shift indexing
#define TSZ  (CIN*TROWS*TCOLS)  // 4096 floats = 16 KB LDS

#define NCOPY 32                // scattered stat accumulator copies (32 x 128 doubles)
#define GRID  (NB*14*8)         // 896 blocks x 8 waves = 7168 waves = 7/SIMD (~87% occ)

// Block = 512 threads = 8 waves: wave w -> khalf = w&1 (cc 0-15 / 16-31),
// chpair = w>>1 (2 output channels). khalf partials are combined through LDS
// so the full 32-cc sum (needed for sum-of-squares) lives in khalf0's registers.
__global__ __launch_bounds__(512) void adder_stats_kernel(
    const float* __restrict__ x, const float* __restrict__ Wt,
    float* __restrict__ raw, double* __restrict__ Sbuf)
{
    __shared__ float xs[TSZ];
    const int t     = threadIdx.x;
    const int bid   = blockIdx.x;
    const int chgrp = bid & 7;
    const int sp    = bid >> 3;          // spatial tile: rp + 14*n  (0..111)
    const int rp    = sp % 14;
    const int n     = sp / 14;
    const int h0    = rp * 2;
    const int copy  = sp & (NCOPY-1);    // spreads each channel's adds over copies

    // ---- stage x strip: ALL 32 channels, rows h0-1..h0+2, cols -1..30 ----
    #pragma unroll
    for (int i = t; i < TSZ; i += 512) {   // 8 exact iterations
        int cc  = i >> 7;          // /128
        int r   = (i >> 5) & 3;    // /32 % 4
        int col = i & 31;
        int hh  = h0 - 1 + r;
        int ww  = col - 1;
        float v = 0.0f;
        if (hh >= 0 && hh < HH && (unsigned)ww < (unsigned)WW)
            v = x[((n*CIN + cc)*HH + hh)*WW + ww];
        xs[i] = v;
    }
    __syncthreads();

    const int lane   = t & 63;
    const int w      = __builtin_amdgcn_readfirstlane(t >> 6); // wave id, uniform
    const int khalf  = w & 1;
    const int chpair = w >> 1;            // 0..3
    const bool valid = lane < 56;         // 2 rows x 28 cols
    const int p      = valid ? lane : 0;
    const int pr     = p / WW;            // 0 or 1
    const int pw     = p % WW;
    const int o_base = chgrp*8 + chpair*2;
    const int b0     = pr*TCOLS + pw;     // base inside channel 0
    const int c0     = khalf * 16;

    float acc0 = 0.0f, acc1 = 0.0f;

    // 16 cc per wave: 9 LDS reads feed 36 VALU; unroll 4 keeps independent
    // ds_read/s_load batches in flight.
    #pragma unroll 4
    for (int k = 0; k < 16; ++k) {
        const int cc = c0 + k;
        float xr[9];
        #pragma unroll
        for (int dr = 0; dr < 3; ++dr)
            #pragma unroll
            for (int dc = 0; dc < 3; ++dc)
                xr[dr*3+dc] = xs[(cc << 7) + b0 + (dr << 5) + dc];
        const float* wp0 = Wt + ((o_base    )*CIN + cc)*9; // wave-uniform -> s_load
        const float* wp1 = Wt + ((o_base + 1)*CIN + cc)*9;
        #pragma unroll
        for (int j = 0; j < 9; ++j) acc0 += __builtin_fabsf(xr[j] - wp0[j]);
        #pragma unroll
        for (int j = 0; j < 9; ++j) acc1 += __builtin_fabsf(xr[j] - wp1[j]);
    }

    // ---- combine khalf partials through LDS (overlaid on xs, now dead) ----
    __syncthreads();                       // everyone done reading xs
    if (khalf == 1 && valid) {
        xs[chpair*112 +      lane] = acc0; // lane==p for valid lanes
        xs[chpair*112 + 56 + lane] = acc1;
    }
    __syncthreads();

    if (khalf == 0) {
        if (valid) {
            acc0 += xs[chpair*112 +      lane];
            acc1 += xs[chpair*112 + 56 + lane];
        }
        // full 32-cc sums now in registers; negate once
        float v0 = valid ? -acc0 : 0.0f;
        float v1 = valid ? -acc1 : 0.0f;

        // write raw
        if (valid) {
            const int base = (h0 + pr)*WW + pw;
            raw[(n*OC + o_base    )*HWSZ + base] = v0;
            raw[(n*OC + o_base + 1)*HWSZ + base] = v1;
        }

        // fused BN stats: f32 wave-reduce, f64 atomics scattered over NCOPY
        float s0 = v0, q0 = v0*v0, s1 = v1, q1 = v1*v1;
        #pragma unroll
        for (int off = 32; off >= 1; off >>= 1) {
            s0 += __shfl_xor(s0, off, 64);
            q0 += __shfl_xor(q0, off, 64);
            s1 += __shfl_xor(s1, off, 64);
            q1 += __shfl_xor(q1, off, 64);
        }
        if (lane == 0) {
            double* Sc = Sbuf + copy*128;
            atomicAdd(&Sc[     o_base    ], (double)s0);
            atomicAdd(&Sc[64 + o_base    ], (double)q0);
            atomicAdd(&Sc[     o_base + 1], (double)s1);
            atomicAdd(&Sc[64 + o_base + 1], (double)q1);
        }
    }
}

// One block per (n,o): stat reduction is wave-uniform (scalar loads + one
// f64 finalize), then 196 float4s of raw -> out.
__global__ __launch_bounds__(256) void bn_kernel(
    const float* __restrict__ raw, const double* __restrict__ Sbuf,
    const float* __restrict__ gamma, const float* __restrict__ beta,
    float* __restrict__ out)
{
    const int no = blockIdx.x;           // n*OC + o
    const int o  = no & (OC - 1);
    double S = 0.0, S2 = 0.0;
    #pragma unroll
    for (int k = 0; k < NCOPY; ++k) {    // o uniform -> scalar loads, L2 broadcast
        S  += Sbuf[k*128 + o];
        S2 += Sbuf[k*128 + 64 + o];
    }
    double mean = S  * (1.0 / CNT);
    double var  = S2 * (1.0 / CNT) - mean * mean;
    double gs   = (double)gamma[o] / sqrt(var + 1e-5);
    const float scl = (float)gs;
    const float sh  = (float)((double)beta[o] - mean * gs);

    const int t = threadIdx.x;
    if (t < HWSZ/4) {                    // 196 float4s per (n,o) plane
        float4 a = ((const float4*)raw)[no*(HWSZ/4) + t];
        float4 v;
        v.x = a.x * scl + sh;
        v.y = a.y * scl + sh;
        v.z = a.z * scl + sh;
        v.w = a.w * scl + sh;
        ((float4*)out)[no*(HWSZ/4) + t] = v;
    }
}

extern "C" void kernel_launch(void* const* d_in, const int* in_sizes, int n_in,
                              void* d_out, int out_size, void* d_ws, size_t ws_size,
                              hipStream_t stream) {
    const float* x     = (const float*)d_in[0];
    const float* Wt    = (const float*)d_in[1];
    const float* gamma = (const float*)d_in[2];
    const float* beta  = (const float*)d_in[3];
    float* out = (float*)d_out;

    // ws layout: [0, 32768)  Sbuf: NCOPY x (64 S + 64 S2) doubles
    //            [32768, 32768+TOTAL*4) raw
    double* Sbuf = (double*)d_ws;
    float*  raw  = (float*)((char*)d_ws + NCOPY*128*sizeof(double));

    hipMemsetAsync(d_ws, 0, NCOPY*128*sizeof(double), stream);
    adder_stats_kernel<<<GRID, 512, 0, stream>>>(x, Wt, raw, Sbuf);
    bn_kernel<<<NB*OC, 256, 0, stream>>>(raw, Sbuf, gamma, beta, out);
}

// Round 6
// 79.160 us; speedup vs baseline: 1.8372x; 1.0200x over previous
//
#include <hip/hip_runtime.h>

#define NB   8
#define CIN  32
#define HH   28
#define WW   28
#define OC   64
#define HWSZ (HH*WW)            // 784
#define TOTAL (NB*OC*HWSZ)      // 401408
#define CNT  (NB*HWSZ)          // 6272 elements per channel for BN stats

#define TROWS 4                 // staged input rows: h0-1 .. h0+2
#define TCOLS 32                // padded cols (-1..30); power-of-2 -> shift indexing
#define TSZ  (CIN*TROWS*TCOLS)  // 4096 floats = 16 KB LDS

#define NSP  (NB*14)            // 112 spatial tiles -> one stat slot each (no atomics)
#define GRID (NSP*8)            // 896 blocks x 8 waves

// wave w of 8: kq = w&3 (cc-quarter, 8 cc), cp = w>>2 (4 output channels each).
// Weights live distributed across lanes in 8 VGPRs/thread; inner loop uses
// v_readlane (compile-time lanes) -> NO smem/vmem in the loop, DS-only lgkm.
__device__ __forceinline__ float rl(float v, int l) {
    return __int_as_float(__builtin_amdgcn_readlane(__float_as_int(v), l));
}

__global__ __launch_bounds__(512) void adder_stats_kernel(
    const float* __restrict__ x, const float* __restrict__ Wt,
    float* __restrict__ raw, double* __restrict__ Sbuf)
{
    __shared__ float xs[TSZ];
    const int t     = threadIdx.x;
    const int bid   = blockIdx.x;
    const int chgrp = bid & 7;
    const int sp    = bid >> 3;          // spatial tile: rp + 14*n  (0..111)
    const int rp    = sp % 14;
    const int n     = sp / 14;
    const int h0    = rp * 2;

    const int lane  = t & 63;
    const int w     = __builtin_amdgcn_readfirstlane(t >> 6);
    const int kq    = w & 3;             // cc-quarter (8 cc)
    const int cp    = w >> 2;            // channel-group-of-4 (0..1)
    const int o_base = chgrp*8 + cp*4;

    // ---- per-lane weight preload: 4 ch x 72 consecutive floats, coalesced ----
    // vw0[r] lane L holds Wt[run+L]; vw1[r] lane L holds Wt[run+64+(L&7)]
    float vw0[4], vw1[4];
    #pragma unroll
    for (int r = 0; r < 4; ++r) {
        const int run = (o_base + r)*(CIN*9) + kq*72;
        vw0[r] = Wt[run + lane];
        vw1[r] = Wt[run + 64 + (lane & 7)];   // stays in-bounds for all lanes
    }

    // ---- stage x strip: ALL 32 channels, rows h0-1..h0+2, cols -1..30 ----
    #pragma unroll
    for (int i = t; i < TSZ; i += 512) {   // 8 exact iterations
        int cc  = i >> 7;
        int r   = (i >> 5) & 3;
        int col = i & 31;
        int hh  = h0 - 1 + r;
        int ww2 = col - 1;
        float v = 0.0f;
        if (hh >= 0 && hh < HH && (unsigned)ww2 < (unsigned)WW)
            v = x[((n*CIN + cc)*HH + hh)*WW + ww2];
        xs[i] = v;
    }
    __syncthreads();

    const bool valid = lane < 56;        // 2 rows x 28 cols
    const int p  = valid ? lane : 0;
    const int pr = p / WW;               // 0 or 1
    const int pw = p % WW;
    const int b0 = pr*TCOLS + pw;

    float acc[4] = {0.f, 0.f, 0.f, 0.f};

    // 8 cc per wave: 9 ds_reads feed 4ch*18 = 72 arith; weights via readlane.
    #pragma unroll
    for (int k = 0; k < 8; ++k) {
        const int cc = kq*8 + k;
        float xr[9];
        #pragma unroll
        for (int dr = 0; dr < 3; ++dr)
            #pragma unroll
            for (int dc = 0; dc < 3; ++dc)
                xr[dr*3+dc] = xs[(cc << 7) + b0 + (dr << 5) + dc];
        #pragma unroll
        for (int r = 0; r < 4; ++r) {
            #pragma unroll
            for (int j = 0; j < 9; ++j) {
                const int e = k*9 + j;                 // 0..71, compile-time
                const float wv = (e < 64) ? rl(vw0[r], e) : rl(vw1[r], e - 64);
                acc[r] += __builtin_fabsf(xr[j] - wv);
            }
        }
    }

    // ---- combine kq partials through LDS (xs now dead); all waves barrier ----
    __syncthreads();
    if (kq != 0 && valid) {
        #pragma unroll
        for (int r = 0; r < 4; ++r)
            xs[((kq-1)*8 + cp*4 + r)*56 + lane] = acc[r];
    }
    __syncthreads();

    if (kq == 0) {
        const int base = (h0 + pr)*WW + pw;
        #pragma unroll
        for (int r = 0; r < 4; ++r) {
            if (valid)
                acc[r] += xs[(     cp*4 + r)*56 + lane]
                        + xs[( 8 + cp*4 + r)*56 + lane]
                        + xs[(16 + cp*4 + r)*56 + lane];
            float v = valid ? -acc[r] : 0.0f;
            if (valid)
                raw[(n*OC + o_base + r)*HWSZ + base] = v;
            // BN stats: f32 wave-reduce, one private f64 slot per (sp, ch)
            float s = v, q = v*v;
            #pragma unroll
            for (int off = 32; off >= 1; off >>= 1) {
                s += __shfl_xor(s, off, 64);
                q += __shfl_xor(q, off, 64);
            }
            if (lane == 0) {
                Sbuf[sp*128 +      o_base + r] = (double)s;
                Sbuf[sp*128 + 64 + o_base + r] = (double)q;
            }
        }
    }
}

// One block per (n,o): lane-parallel reduction of the 112 stat slots, then
// 196 float4s of raw -> out.
__global__ __launch_bounds__(256) void bn_kernel(
    const float* __restrict__ raw, const double* __restrict__ Sbuf,
    const float* __restrict__ gamma, const float* __restrict__ beta,
    float* __restrict__ out)
{
    __shared__ double dsum[4];
    __shared__ float  sb[2];
    const int no = blockIdx.x;           // n*OC + o
    const int o  = no & (OC - 1);
    const int t  = threadIdx.x;

    if (t < 128) {
        double s = 0.0, q = 0.0;
        if (t < NSP) {                   // 112 slots, one per lane
            s = Sbuf[t*128 +      o];
            q = Sbuf[t*128 + 64 + o];
        }
        #pragma unroll
        for (int off = 32; off >= 1; off >>= 1) {
            s += __shfl_xor(s, off, 64);
            q += __shfl_xor(q, off, 64);
        }
        if ((t & 63) == 0) { dsum[t>>6] = s; dsum[2 + (t>>6)] = q; }
    }
    __syncthreads();
    if (t == 0) {
        double S  = dsum[0] + dsum[1];
        double S2 = dsum[2] + dsum[3];
        double mean = S  * (1.0 / CNT);
        double var  = S2 * (1.0 / CNT) - mean * mean;
        double gs   = (double)gamma[o] / sqrt(var + 1e-5);
        sb[0] = (float)gs;
        sb[1] = (float)((double)beta[o] - mean * gs);
    }
    __syncthreads();
    const float scl = sb[0], sh = sb[1];
    if (t < HWSZ/4) {                    // 196 float4s per (n,o) plane
        float4 a = ((const float4*)raw)[no*(HWSZ/4) + t];
        float4 v;
        v.x = a.x * scl + sh;
        v.y = a.y * scl + sh;
        v.z = a.z * scl + sh;
        v.w = a.w * scl + sh;
        ((float4*)out)[no*(HWSZ/4) + t] = v;
    }
}

extern "C" void kernel_launch(void* const* d_in, const int* in_sizes, int n_in,
                              void* d_out, int out_size, void* d_ws, size_t ws_size,
                              hipStream_t stream) {
    const float* x     = (const float*)d_in[0];
    const float* Wt    = (const float*)d_in[1];
    const float* gamma = (const float*)d_in[2];
    const float* beta  = (const float*)d_in[3];
    float* out = (float*)d_out;

    // ws layout: [0, 114688)  Sbuf: 112 x (64 S + 64 S2) doubles (every slot
    //            rewritten each iteration -> no zeroing / no memset dispatch)
    //            [131072, 131072+TOTAL*4) raw
    double* Sbuf = (double*)d_ws;
    float*  raw  = (float*)((char*)d_ws + 131072);

    adder_stats_kernel<<<GRID, 512, 0, stream>>>(x, Wt, raw, Sbuf);
    bn_kernel<<<NB*OC, 256, 0, stream>>>(raw, Sbuf, gamma, beta, out);
}